// Round 8
// baseline (270.360 us; speedup 1.0000x reference)
//
#include <hip/hip_runtime.h>

#define NN 100000
#define NE 1600000
#define NB 782          // ceil(NN/128) coarse buckets, 128 nodes each
#define CHUNK 4096      // 391 chunks: 2x blocks vs r6 (grid-starvation fix)
#define CAP 6144        // bsort LDS staging cap (bucket avg ~2046 sigma ~45)

typedef __attribute__((ext_vector_type(8))) short bf16x8;
typedef __attribute__((ext_vector_type(4))) float f32x4;

static __device__ __forceinline__ unsigned short f2bf(float f) {
  unsigned int u = __float_as_uint(f);
  u += 0x7fff + ((u >> 16) & 1);       // round-to-nearest-even
  return (unsigned short)(u >> 16);
}

static __device__ __forceinline__ bf16x8 cvt8(float4 lo, float4 hi) {
  union { unsigned short s[8]; bf16x8 v; } u;
  u.s[0] = f2bf(lo.x); u.s[1] = f2bf(lo.y); u.s[2] = f2bf(lo.z); u.s[3] = f2bf(lo.w);
  u.s[4] = f2bf(hi.x); u.s[5] = f2bf(hi.y); u.s[6] = f2bf(hi.z); u.s[7] = f2bf(hi.w);
  return u.v;
}

// One-time: wt[c][k] = bf16(W[k][c]), combined cols (c<64 -> W_l, c>=64 -> W_r)
__global__ void wprep_k(const float* __restrict__ wl, const float* __restrict__ wr,
                        unsigned short* __restrict__ wt) {
  int i = blockIdx.x * 256 + threadIdx.x;     // 16384
  int c = i >> 7, k = i & 127;
  float v = (c < 64) ? wl[k * 64 + c] : wr[k * 64 + (c - 64)];
  wt[i] = f2bf(v);
}

// MFMA bf16 GEMM, 128-row tiles, ZERO LDS: A direct global->reg + in-reg cvt
// (A-fragments are wave-private, staging bought nothing); B 16B-frag loads
// from L1/L2-resident wt (16 KB). No barriers.
__global__ __launch_bounds__(256) void gemm_mfma(const float* __restrict__ feat,
                                                 const unsigned short* __restrict__ wt,
                                                 float* __restrict__ hl,
                                                 unsigned short* __restrict__ hrb) {
  const int tid = threadIdx.x;
  const int row0 = blockIdx.x * 128;
  const int w  = tid >> 6;          // wave 0..3 owns rows w*32..w*32+31
  const int ln = tid & 63;
  const int lr = ln & 15;
  const int kb = (ln >> 4) * 8;     // k-octet within a 32-wide K-step

  const int r0g = row0 + w * 32 + lr;
  const int r1g = r0g + 16;
  const bool ok0 = r0g < NN, ok1 = r1g < NN;
  const float4 zero4 = make_float4(0.f, 0.f, 0.f, 0.f);

  f32x4 acc[2][8];
#pragma unroll
  for (int mt = 0; mt < 2; ++mt)
#pragma unroll
    for (int nt = 0; nt < 8; ++nt) acc[mt][nt] = (f32x4){0.f, 0.f, 0.f, 0.f};

#pragma unroll
  for (int t = 0; t < 4; ++t) {
    const int ko = t * 32 + kb;
    float4 a0l = ok0 ? *reinterpret_cast<const float4*>(&feat[(size_t)r0g * 128 + ko]) : zero4;
    float4 a0h = ok0 ? *reinterpret_cast<const float4*>(&feat[(size_t)r0g * 128 + ko + 4]) : zero4;
    float4 a1l = ok1 ? *reinterpret_cast<const float4*>(&feat[(size_t)r1g * 128 + ko]) : zero4;
    float4 a1h = ok1 ? *reinterpret_cast<const float4*>(&feat[(size_t)r1g * 128 + ko + 4]) : zero4;
    bf16x8 af0 = cvt8(a0l, a0h);
    bf16x8 af1 = cvt8(a1l, a1h);
    bf16x8 bfr[8];
#pragma unroll
    for (int nt = 0; nt < 8; ++nt)
      bfr[nt] = *reinterpret_cast<const bf16x8*>(&wt[(size_t)(nt * 16 + lr) * 128 + ko]);
#pragma unroll
    for (int nt = 0; nt < 8; ++nt) {
      acc[0][nt] = __builtin_amdgcn_mfma_f32_16x16x32_bf16(af0, bfr[nt], acc[0][nt], 0, 0, 0);
      acc[1][nt] = __builtin_amdgcn_mfma_f32_16x16x32_bf16(af1, bfr[nt], acc[1][nt], 0, 0, 0);
    }
  }

#pragma unroll
  for (int mt = 0; mt < 2; ++mt) {
    int rrel = w * 32 + mt * 16 + (ln >> 4) * 4;
#pragma unroll
    for (int q = 0; q < 4; ++q) {
      int gr = row0 + rrel + q;
      if (gr < NN) {
#pragma unroll
        for (int nt = 0; nt < 4; ++nt)       // cols 0..63 -> h_l (f32)
          hl[(size_t)gr * 64 + nt * 16 + lr] = acc[mt][nt][q];
#pragma unroll
        for (int nt = 4; nt < 8; ++nt)       // cols 64..127 -> h_r (bf16)
          hrb[(size_t)gr * 64 + (nt - 4) * 16 + lr] = f2bf(acc[mt][nt][q]);
      }
    }
  }
}

// Phase A: coarse bucket histogram. Global counters padded to 1/cacheline.
__global__ __launch_bounds__(256) void bhist_k(const int* __restrict__ tgt,
                                               int* __restrict__ bcnt) {
  __shared__ int lh[NB];
  const int tid = threadIdx.x;
  const int base = blockIdx.x * CHUNK;
  const int lim = min(CHUNK, NE - base);
  for (int b = tid; b < NB; b += 256) lh[b] = 0;
  __syncthreads();
  for (int i = tid; i < lim; i += 256)
    atomicAdd(&lh[tgt[base + i] >> 7], 1);
  __syncthreads();
  for (int b = tid; b < NB; b += 256)
    if (lh[b]) atomicAdd(&bcnt[b * 16], lh[b]);
}

// Phase B: exclusive scan of bucket counts (single block)
__global__ __launch_bounds__(256) void bscan_k(const int* __restrict__ bcnt,
                                               int* __restrict__ bstart,
                                               int* __restrict__ bcursor) {
  __shared__ int sd[256];
  const int tid = threadIdx.x;
  int v[4]; int s = 0;
#pragma unroll
  for (int j = 0; j < 4; ++j) {
    int idx = tid * 4 + j;
    v[j] = (idx < NB) ? bcnt[idx * 16] : 0;
    s += v[j];
  }
  sd[tid] = s;
  __syncthreads();
  for (int off = 1; off < 256; off <<= 1) {
    int t = (tid >= off) ? sd[tid - off] : 0;
    __syncthreads();
    sd[tid] += t;
    __syncthreads();
  }
  int run = sd[tid] - s;
#pragma unroll
  for (int j = 0; j < 4; ++j) {
    int idx = tid * 4 + j;
    if (idx < NB) { bstart[idx] = run; bcursor[idx * 16] = run; }
    run += v[j];
  }
  if (tid == 255) bstart[NB] = NE;
}

// Phase C: bucket-partition edges. LDS-staged; padded reservation atomics;
// index-parallel bucket-contiguous writeout. rec = (src<<7)|tgt_local.
__global__ __launch_bounds__(256) void bscatter_k(const int* __restrict__ edge,
                                                  int* __restrict__ bcursor,
                                                  int* __restrict__ brec) {
  __shared__ int lcnt[NB];
  __shared__ int lstart[NB];
  __shared__ int gbase[NB];
  __shared__ int lcur[NB];
  __shared__ int srec[CHUNK];
  __shared__ unsigned short bid[CHUNK];
  __shared__ int sd[256];
  const int tid = threadIdx.x;
  const int base = blockIdx.x * CHUNK;
  const int lim = min(CHUNK, NE - base);

  for (int b = tid; b < NB; b += 256) { lcnt[b] = 0; lcur[b] = 0; }
  __syncthreads();
  for (int i = tid; i < lim; i += 256)
    atomicAdd(&lcnt[edge[NE + base + i] >> 7], 1);
  __syncthreads();

  int v[4]; int s = 0;
#pragma unroll
  for (int j = 0; j < 4; ++j) {
    int idx = tid * 4 + j;
    v[j] = (idx < NB) ? lcnt[idx] : 0;
    s += v[j];
  }
  sd[tid] = s;
  __syncthreads();
  for (int off = 1; off < 256; off <<= 1) {
    int t = (tid >= off) ? sd[tid - off] : 0;
    __syncthreads();
    sd[tid] += t;
    __syncthreads();
  }
  int run = sd[tid] - s;
#pragma unroll
  for (int j = 0; j < 4; ++j) {
    int idx = tid * 4 + j;
    if (idx < NB) lstart[idx] = run;
    run += v[j];
  }
  __syncthreads();

  for (int b = tid; b < NB; b += 256)
    if (lcnt[b] > 0) gbase[b] = atomicAdd(&bcursor[b * 16], lcnt[b]);
  __syncthreads();

  for (int i = tid; i < lim; i += 256) {
    int tg = edge[NE + base + i];
    int sr = edge[base + i];
    int b = tg >> 7;
    int r = atomicAdd(&lcur[b], 1);
    int slot = lstart[b] + r;
    srec[slot] = (sr << 7) | (tg & 127);
    bid[slot] = (unsigned short)b;
  }
  __syncthreads();

  for (int i = tid; i < lim; i += 256) {
    int b = bid[i];
    brec[gbase[b] + i - lstart[b]] = srec[i];
  }
}

// Phase D: in-place node-level sort within each bucket; emits start[].
__global__ __launch_bounds__(256) void bsort_k(int* __restrict__ brec,
                                               const int* __restrict__ bstart,
                                               int* __restrict__ start) {
  __shared__ int srec[CAP];
  __shared__ int ncnt[128];
  __shared__ int nst[128];
  __shared__ int sd2[128];
  const int tid = threadIdx.x;
  const int b = blockIdx.x;
  const int s0 = bstart[b];
  const int cnt = bstart[b + 1] - s0;

  if (tid < 128) ncnt[tid] = 0;
  __syncthreads();
  for (int i = tid; i < cnt; i += 256) {
    int r = brec[s0 + i];
    srec[i] = r;
    atomicAdd(&ncnt[r & 127], 1);
  }
  __syncthreads();

  int val = (tid < 128) ? ncnt[tid] : 0;
  if (tid < 128) sd2[tid] = val;
  __syncthreads();
  for (int off = 1; off < 128; off <<= 1) {
    int t = 0;
    if (tid < 128 && tid >= off) t = sd2[tid - off];
    __syncthreads();
    if (tid < 128) sd2[tid] += t;
    __syncthreads();
  }
  if (tid < 128) {
    nst[tid] = sd2[tid] - val;
    int nid = (b << 7) + tid;
    if (nid < NN) start[nid] = s0 + nst[tid];
    ncnt[tid] = 0;                       // reuse as cursor
  }
  if (b == NB - 1 && tid == 0) start[NN] = NE;
  __syncthreads();

  for (int i = tid; i < cnt; i += 256) {
    int r = srec[i];
    int tl = r & 127;
    int p = atomicAdd(&ncnt[tl], 1);
    brec[s0 + nst[tl] + p] = r >> 7;     // final: grouped src ids
  }
}

// One wave per node; 16 lanes per edge (4 heads x float4), 8 edges in flight.
// h_r gathered as bf16 (8B/lane, 128B/edge).
__global__ __launch_bounds__(256) void node_k(const float* __restrict__ hl,
                                              const unsigned short* __restrict__ hrb,
                                              const int* __restrict__ ssrc,
                                              const int* __restrict__ start,
                                              const float* __restrict__ att,
                                              const float* __restrict__ bias,
                                              float* __restrict__ out) {
  const int lane = threadIdx.x & 63;
  const int n  = blockIdx.x * 4 + (threadIdx.x >> 6);
  const int g  = lane >> 4;          // edge slot 0..3
  const int fo = (lane & 15) * 4;    // (head,feature-quad) offset within 64

  const float4 xi = *reinterpret_cast<const float4*>(hl + (size_t)n * 64 + fo);
  const float4 a  = *reinterpret_cast<const float4*>(att + fo);
  const int s = start[n];
  const int e = start[n + 1];
  const unsigned short* __restrict__ hrp = hrb + fo;

  float  den = 0.f;
  float4 acc = make_float4(0.f, 0.f, 0.f, 0.f);

  for (int i = s; i < e; i += 8) {
    int r0 = i + g, r1 = i + 4 + g;
    bool v0 = r0 < e, v1 = r1 < e;
    int j0 = ssrc[v0 ? r0 : s];
    int j1 = ssrc[v1 ? r1 : s];
    uint2 p0 = *reinterpret_cast<const uint2*>(hrp + (size_t)j0 * 64);
    uint2 p1 = *reinterpret_cast<const uint2*>(hrp + (size_t)j1 * 64);
    float4 x0, x1;
    x0.x = __uint_as_float(p0.x << 16);
    x0.y = __uint_as_float(p0.x & 0xffff0000u);
    x0.z = __uint_as_float(p0.y << 16);
    x0.w = __uint_as_float(p0.y & 0xffff0000u);
    x1.x = __uint_as_float(p1.x << 16);
    x1.y = __uint_as_float(p1.x & 0xffff0000u);
    x1.z = __uint_as_float(p1.y << 16);
    x1.w = __uint_as_float(p1.y & 0xffff0000u);

    float4 z0, z1;
    z0.x = xi.x + x0.x; z0.y = xi.y + x0.y; z0.z = xi.z + x0.z; z0.w = xi.w + x0.w;
    z1.x = xi.x + x1.x; z1.y = xi.y + x1.y; z1.z = xi.z + x1.z; z1.w = xi.w + x1.w;
    z0.x = fmaxf(z0.x, 0.2f * z0.x); z0.y = fmaxf(z0.y, 0.2f * z0.y);
    z0.z = fmaxf(z0.z, 0.2f * z0.z); z0.w = fmaxf(z0.w, 0.2f * z0.w);
    z1.x = fmaxf(z1.x, 0.2f * z1.x); z1.y = fmaxf(z1.y, 0.2f * z1.y);
    z1.z = fmaxf(z1.z, 0.2f * z1.z); z1.w = fmaxf(z1.w, 0.2f * z1.w);

    float t0 = z0.x * a.x; t0 = fmaf(z0.y, a.y, t0);
    t0 = fmaf(z0.z, a.z, t0); t0 = fmaf(z0.w, a.w, t0);
    float t1 = z1.x * a.x; t1 = fmaf(z1.y, a.y, t1);
    t1 = fmaf(z1.z, a.z, t1); t1 = fmaf(z1.w, a.w, t1);

    t0 += __shfl_xor(t0, 1); t0 += __shfl_xor(t0, 2);
    t1 += __shfl_xor(t1, 1); t1 += __shfl_xor(t1, 2);

    float e0 = v0 ? __expf(t0) : 0.f;
    float e1 = v1 ? __expf(t1) : 0.f;
    den += e0 + e1;
    acc.x = fmaf(e0, x0.x, acc.x); acc.y = fmaf(e0, x0.y, acc.y);
    acc.z = fmaf(e0, x0.z, acc.z); acc.w = fmaf(e0, x0.w, acc.w);
    acc.x = fmaf(e1, x1.x, acc.x); acc.y = fmaf(e1, x1.y, acc.y);
    acc.z = fmaf(e1, x1.z, acc.z); acc.w = fmaf(e1, x1.w, acc.w);
  }

#pragma unroll
  for (int m = 16; m <= 32; m <<= 1) {
    den   += __shfl_xor(den, m);
    acc.x += __shfl_xor(acc.x, m);
    acc.y += __shfl_xor(acc.y, m);
    acc.z += __shfl_xor(acc.z, m);
    acc.w += __shfl_xor(acc.w, m);
  }

  if (g == 0) {
    float inv = (e > s) ? 1.f / den : 0.f;
    float4 b4 = *reinterpret_cast<const float4*>(bias + fo);
    float4 r;
    r.x = fmaf(acc.x, inv, b4.x);
    r.y = fmaf(acc.y, inv, b4.y);
    r.z = fmaf(acc.z, inv, b4.z);
    r.w = fmaf(acc.w, inv, b4.w);
    *reinterpret_cast<float4*>(out + (size_t)n * 64 + fo) = r;
  }
}

extern "C" void kernel_launch(void* const* d_in, const int* in_sizes, int n_in,
                              void* d_out, int out_size, void* d_ws, size_t ws_size,
                              hipStream_t stream) {
  const float* feat = (const float*)d_in[0];
  const int*   edge = (const int*)d_in[1];
  const float* wl   = (const float*)d_in[2];
  const float* wr   = (const float*)d_in[3];
  const float* att  = (const float*)d_in[4];
  const float* bias = (const float*)d_in[5];
  float* out = (float*)d_out;

  // workspace layout (~45.6 MB)
  float* hl       = (float*)d_ws;                        // NN*64 f32
  unsigned short* hrb = (unsigned short*)(hl + (size_t)NN * 64);  // NN*64 bf16
  int*   brec     = (int*)(hrb + (size_t)NN * 64);       // NE
  int*   bcnt     = brec + NE;                           // NB*16 (padded, 1/line)
  int*   bstart   = bcnt + NB * 16;                      // NB+1
  int*   bcursor  = bstart + NB + 1;                     // NB*16 (padded)
  int*   start    = bcursor + NB * 16;                   // NN+1
  unsigned short* wt = (unsigned short*)(start + NN + 1);  // 16384 bf16

  (void)hipMemsetAsync(bcnt, 0, NB * 16 * sizeof(int), stream);

  const int nchunk = (NE + CHUNK - 1) / CHUNK;           // 391
  wprep_k<<<64, 256, 0, stream>>>(wl, wr, wt);
  gemm_mfma<<<(NN + 127) / 128, 256, 0, stream>>>(feat, wt, hl, hrb);
  bhist_k<<<nchunk, 256, 0, stream>>>(edge + NE, bcnt);
  bscan_k<<<1, 256, 0, stream>>>(bcnt, bstart, bcursor);
  bscatter_k<<<nchunk, 256, 0, stream>>>(edge, bcursor, brec);
  bsort_k<<<NB, 256, 0, stream>>>(brec, bstart, start);
  node_k<<<NN / 4, 256, 0, stream>>>(hl, hrb, brec, start, att, bias, out);
}